// Round 2
// baseline (508.177 us; speedup 1.0000x reference)
//
#include <hip/hip_runtime.h>
#include <hip/hip_bf16.h>

// WanSelfAttention: x[1,3584,1536] -> QKV proj -> RMSNorm(full dim) -> 3D RoPE
// -> 12-head attention (HD=128) -> out proj. All matmuls bf16 MFMA, f32 accum.

#define DIM   1536
#define HEADS 12
#define HD    128
#define LSEQ  3584
// 3D rope: f=8, h=16, w=28 ; c=64 pairs; splits [22,21,21]

typedef __bf16 bf16_t;
typedef __attribute__((ext_vector_type(8))) __bf16 bf16x8;
typedef __attribute__((ext_vector_type(4))) float f32x4;

static __device__ __forceinline__ ushort f2bf(float f) {
  bf16_t h = (bf16_t)f;
  return __builtin_bit_cast(ushort, h);
}
static __device__ __forceinline__ float bf2f(ushort u) {
  return (float)__builtin_bit_cast(bf16_t, u);
}

// ---------------- f32 -> bf16 convert ----------------
__global__ __launch_bounds__(256) void cvt_f32_bf16(const float* __restrict__ in,
                                                    ushort* __restrict__ out, int n) {
  int i = (blockIdx.x * 256 + threadIdx.x) * 4;
  if (i + 3 < n) {
    float4 v = *reinterpret_cast<const float4*>(in + i);
    ushort4 o;
    o.x = f2bf(v.x); o.y = f2bf(v.y); o.z = f2bf(v.z); o.w = f2bf(v.w);
    *reinterpret_cast<ushort4*>(out + i) = o;
  }
}

// ---------------- GEMM: C[M][N] = A[M][K] @ B[N][K]^T + bias ----------------
// 128x128 tile, BK=32, 4 waves (2x2), wave tile 64x64 (4x4 16x16 frags).
template <bool OUT_F32>
__global__ __launch_bounds__(256) void gemm_bt(const ushort* __restrict__ A,
                                               const ushort* __restrict__ B,
                                               const float* __restrict__ bias,
                                               void* __restrict__ Cout,
                                               int M, int N, int K) {
  __shared__ __attribute__((aligned(16))) ushort As[128 * 32];
  __shared__ __attribute__((aligned(16))) ushort Bs[128 * 32];
  const int tid  = threadIdx.x;
  const int lane = tid & 63;
  const int wid  = tid >> 6;
  const int m0 = blockIdx.x * 128;
  const int n0 = blockIdx.y * 128;
  const int wm = (wid >> 1) * 64;
  const int wn = (wid & 1) * 64;
  const int lr = lane & 15;   // frag row/col within 16
  const int lg = lane >> 4;   // k-chunk selector
  const int crow = lane >> 2;        // staging: row within 16-row chunk
  const int ccol = (lane & 3) * 8;   // staging: 8-elem col chunk

  f32x4 acc[4][4] = {};

  for (int kt = 0; kt < K; kt += 32) {
    __syncthreads();
    // stage A and B tiles: each wave moves 2x 1KB chunks of each via global_load_lds
#pragma unroll
    for (int i = 0; i < 2; ++i) {
      int chunk = wid * 2 + i;                   // 0..7 -> rows [chunk*16, +16)
      int row = chunk * 16 + crow;
      const ushort* ga = A + (size_t)(m0 + row) * K + kt + ccol;
      const ushort* gb = B + (size_t)(n0 + row) * K + kt + ccol;
      __builtin_amdgcn_global_load_lds(
          (__attribute__((address_space(1))) void*)(void*)ga,
          (__attribute__((address_space(3))) void*)(&As[chunk * 512]), 16, 0, 0);
      __builtin_amdgcn_global_load_lds(
          (__attribute__((address_space(1))) void*)(void*)gb,
          (__attribute__((address_space(3))) void*)(&Bs[chunk * 512]), 16, 0, 0);
    }
    __syncthreads();

    bf16x8 af[4], bf[4];
#pragma unroll
    for (int m = 0; m < 4; ++m)
      af[m] = *reinterpret_cast<const bf16x8*>(&As[(wm + m * 16 + lr) * 32 + lg * 8]);
#pragma unroll
    for (int n = 0; n < 4; ++n)
      bf[n] = *reinterpret_cast<const bf16x8*>(&Bs[(wn + n * 16 + lr) * 32 + lg * 8]);
#pragma unroll
    for (int m = 0; m < 4; ++m)
#pragma unroll
      for (int n = 0; n < 4; ++n)
        acc[m][n] = __builtin_amdgcn_mfma_f32_16x16x32_bf16(af[m], bf[n], acc[m][n], 0, 0, 0);
  }

#pragma unroll
  for (int m = 0; m < 4; ++m) {
#pragma unroll
    for (int n = 0; n < 4; ++n) {
      int col = n0 + wn + n * 16 + lr;
      float bv = bias[col];
#pragma unroll
      for (int r = 0; r < 4; ++r) {
        int row = m0 + wm + m * 16 + lg * 4 + r;
        float v = acc[m][n][r] + bv;
        if (OUT_F32)
          ((float*)Cout)[(size_t)row * N + col] = v;
        else
          ((ushort*)Cout)[(size_t)row * N + col] = f2bf(v);
      }
    }
  }
}

// ---------------- RMSNorm(full 1536) + 3D RoPE, in place on bf16 ----------------
__global__ __launch_bounds__(256) void normrope(ushort* __restrict__ Qb,
                                                ushort* __restrict__ Kb,
                                                const float* __restrict__ gq,
                                                const float* __restrict__ gk,
                                                const float* __restrict__ cosT,
                                                const float* __restrict__ sinT) {
  __shared__ float red[4];
  const int l = blockIdx.x;
  const int tid = threadIdx.x;
  ushort* row = (blockIdx.y == 0 ? Qb : Kb) + (size_t)l * DIM;
  const float* g = blockIdx.y == 0 ? gq : gk;

  // load 6 elems (3 bf16 pairs) per thread
  const uint* rp = reinterpret_cast<const uint*>(row);
  uint pk[3];
  float v[6];
#pragma unroll
  for (int i = 0; i < 3; ++i) {
    pk[i] = rp[tid * 3 + i];
    v[2 * i]     = bf2f((ushort)(pk[i] & 0xffff));
    v[2 * i + 1] = bf2f((ushort)(pk[i] >> 16));
  }
  float ss = 0.f;
#pragma unroll
  for (int i = 0; i < 6; ++i) ss += v[i] * v[i];
#pragma unroll
  for (int off = 1; off < 64; off <<= 1) ss += __shfl_xor(ss, off, 64);
  if ((tid & 63) == 0) red[tid >> 6] = ss;
  __syncthreads();
  float tot = red[0] + red[1] + red[2] + red[3];
  float rms = rsqrtf(tot * (1.0f / DIM) + 1e-6f);

  const int fi = l / 448;          // f index (h*w = 448)
  const int rem = l % 448;
  const int hi = rem / 28;
  const int wi = rem % 28;

  uint* wp = reinterpret_cast<uint*>(row);
#pragma unroll
  for (int i = 0; i < 3; ++i) {
    int p = tid * 3 + i;          // global pair index 0..767
    int head = p >> 6;
    int j = p & 63;               // pair index within head, 0..63
    int trow = (j < 22) ? fi : ((j < 43) ? hi : wi);
    float cv = cosT[trow * 64 + j];
    float sv = sinT[trow * 64 + j];
    int idx = head * 128 + 2 * j;
    float xr = v[2 * i] * rms * g[idx];
    float xi = v[2 * i + 1] * rms * g[idx + 1];
    float orr = xr * cv - xi * sv;
    float oii = xr * sv + xi * cv;
    wp[p] = (uint)f2bf(orr) | ((uint)f2bf(oii) << 16);
  }
}

// ---------------- flash attention ----------------
// grid (L/64, HEADS); 4 waves; wave owns 16 Q rows; KV tile = 32.
__global__ __launch_bounds__(256) void attn(const ushort* __restrict__ Q,
                                            const ushort* __restrict__ Kp,
                                            const ushort* __restrict__ Vp,
                                            ushort* __restrict__ O) {
  __shared__ __attribute__((aligned(16))) ushort Ks[32][136];   // K tile, padded
  __shared__ __attribute__((aligned(16))) ushort Vs[128][40];   // V tile transposed [d][k]
  __shared__ __attribute__((aligned(16))) ushort Ps[4][16][40]; // per-wave P tile
  const int tid  = threadIdx.x;
  const int lane = tid & 63;
  const int wv   = tid >> 6;
  const int h    = blockIdx.y;
  const int q0   = blockIdx.x * 64;
  const int lr = lane & 15;
  const int lg = lane >> 4;
  const float scale = 0.08838834764831845f; // 1/sqrt(128)

  // Q fragments stay in registers (16 q-rows x 128 d per wave)
  bf16x8 qf[4];
  {
    const ushort* qrow = Q + (size_t)(q0 + wv * 16 + lr) * DIM + h * HD;
#pragma unroll
    for (int kk = 0; kk < 4; ++kk)
      qf[kk] = *reinterpret_cast<const bf16x8*>(qrow + kk * 32 + lg * 8);
  }

  f32x4 accO[8] = {};
  float mrow[4], lrow[4];
#pragma unroll
  for (int r = 0; r < 4; ++r) { mrow[r] = -INFINITY; lrow[r] = 0.f; }

  for (int kv0 = 0; kv0 < LSEQ; kv0 += 32) {
    __syncthreads();
    // K tile [32][128] -> LDS (padded rows)
#pragma unroll
    for (int i = 0; i < 2; ++i) {
      int c = tid + i * 256;
      int row = c >> 4, dc = (c & 15) * 8;
      uint4 kvv = *reinterpret_cast<const uint4*>(Kp + (size_t)(kv0 + row) * DIM + h * HD + dc);
      *reinterpret_cast<uint4*>(&Ks[row][dc]) = kvv;
    }
    // V tile transposed: Vs[d][k]
#pragma unroll
    for (int i = 0; i < 2; ++i) {
      int k = tid & 31;
      int dch = (tid >> 5) + i * 8;
      uint4 vv = *reinterpret_cast<const uint4*>(Vp + (size_t)(kv0 + k) * DIM + h * HD + dch * 8);
      const ushort* pv = reinterpret_cast<const ushort*>(&vv);
#pragma unroll
      for (int j = 0; j < 8; ++j) Vs[dch * 8 + j][k] = pv[j];
    }
    __syncthreads();

    // S = Q K^T : 16x32 per wave, 2 col-tiles x 4 k-steps
    f32x4 sc[2];
#pragma unroll
    for (int c = 0; c < 2; ++c) {
      sc[c] = f32x4{0.f, 0.f, 0.f, 0.f};
#pragma unroll
      for (int kk = 0; kk < 4; ++kk) {
        bf16x8 kf = *reinterpret_cast<const bf16x8*>(&Ks[c * 16 + lr][kk * 32 + lg * 8]);
        sc[c] = __builtin_amdgcn_mfma_f32_16x16x32_bf16(qf[kk], kf, sc[c], 0, 0, 0);
      }
    }

    // online softmax (row = lg*4+r, cols spread over 16 lanes of the group)
    float p[2][4];
#pragma unroll
    for (int r = 0; r < 4; ++r) {
      float s0 = sc[0][r] * scale, s1 = sc[1][r] * scale;
      float mt = fmaxf(s0, s1);
#pragma unroll
      for (int off = 1; off < 16; off <<= 1) mt = fmaxf(mt, __shfl_xor(mt, off, 16));
      float mn = fmaxf(mrow[r], mt);
      float al = __expf(mrow[r] - mn);
      mrow[r] = mn;
      float p0 = __expf(s0 - mn), p1 = __expf(s1 - mn);
      float rs = p0 + p1;
#pragma unroll
      for (int off = 1; off < 16; off <<= 1) rs += __shfl_xor(rs, off, 16);
      lrow[r] = lrow[r] * al + rs;
      p[0][r] = p0; p[1][r] = p1;
#pragma unroll
      for (int c2 = 0; c2 < 8; ++c2) accO[c2][r] *= al;
    }

    // P -> LDS (per-wave region), acc layout -> A-frag layout
#pragma unroll
    for (int c = 0; c < 2; ++c)
#pragma unroll
      for (int r = 0; r < 4; ++r)
        Ps[wv][lg * 4 + r][c * 16 + lr] = f2bf(p[c][r]);
    __syncthreads();

    // O += P @ V
    bf16x8 pf = *reinterpret_cast<const bf16x8*>(&Ps[wv][lr][lg * 8]);
#pragma unroll
    for (int c2 = 0; c2 < 8; ++c2) {
      bf16x8 vf = *reinterpret_cast<const bf16x8*>(&Vs[c2 * 16 + lr][lg * 8]);
      accO[c2] = __builtin_amdgcn_mfma_f32_16x16x32_bf16(pf, vf, accO[c2], 0, 0, 0);
    }
  }

  // epilogue: O / l
#pragma unroll
  for (int r = 0; r < 4; ++r) {
    float inv = 1.0f / lrow[r];
    int row = q0 + wv * 16 + lg * 4 + r;
    ushort* orow = O + (size_t)row * DIM + h * HD;
#pragma unroll
    for (int c2 = 0; c2 < 8; ++c2)
      orow[c2 * 16 + lr] = f2bf(accO[c2][r] * inv);
  }
}

// ---------------- launch ----------------
extern "C" void kernel_launch(void* const* d_in, const int* in_sizes, int n_in,
                              void* d_out, int out_size, void* d_ws, size_t ws_size,
                              hipStream_t stream) {
  (void)in_sizes; (void)n_in; (void)out_size;
  const float* x    = (const float*)d_in[0];
  const float* cosT = (const float*)d_in[1];
  const float* sinT = (const float*)d_in[2];
  const float* Wq   = (const float*)d_in[3];
  const float* bq   = (const float*)d_in[4];
  const float* Wk   = (const float*)d_in[5];
  const float* bk   = (const float*)d_in[6];
  const float* Wv   = (const float*)d_in[7];
  const float* bv   = (const float*)d_in[8];
  const float* Wo   = (const float*)d_in[9];
  const float* bo   = (const float*)d_in[10];
  const float* gq   = (const float*)d_in[11];
  const float* gk   = (const float*)d_in[12];

  const size_t LD = (size_t)LSEQ * DIM;   // 5,505,024
  const size_t WD = (size_t)DIM * DIM;    // 2,359,296
  if (ws_size < (5 * LD + 4 * WD) * sizeof(ushort)) return;  // ~74 MB needed

  ushort* xb  = (ushort*)d_ws;
  ushort* Wqb = xb + LD;
  ushort* Wkb = Wqb + WD;
  ushort* Wvb = Wkb + WD;
  ushort* Wob = Wvb + WD;
  ushort* Qb  = Wob + WD;
  ushort* Kb  = Qb + LD;
  ushort* Vb  = Kb + LD;
  ushort* Ob  = Vb + LD;

  // converts
  cvt_f32_bf16<<<(int)(LD / 4 / 256), 256, 0, stream>>>(x, xb, (int)LD);
  cvt_f32_bf16<<<(int)(WD / 4 / 256), 256, 0, stream>>>(Wq, Wqb, (int)WD);
  cvt_f32_bf16<<<(int)(WD / 4 / 256), 256, 0, stream>>>(Wk, Wkb, (int)WD);
  cvt_f32_bf16<<<(int)(WD / 4 / 256), 256, 0, stream>>>(Wv, Wvb, (int)WD);
  cvt_f32_bf16<<<(int)(WD / 4 / 256), 256, 0, stream>>>(Wo, Wob, (int)WD);

  dim3 ggrid(LSEQ / 128, DIM / 128);
  gemm_bt<false><<<ggrid, 256, 0, stream>>>(xb, Wqb, bq, Qb, LSEQ, DIM, DIM);
  gemm_bt<false><<<ggrid, 256, 0, stream>>>(xb, Wkb, bk, Kb, LSEQ, DIM, DIM);
  gemm_bt<false><<<ggrid, 256, 0, stream>>>(xb, Wvb, bv, Vb, LSEQ, DIM, DIM);

  normrope<<<dim3(LSEQ, 2), 256, 0, stream>>>(Qb, Kb, gq, gk, cosT, sinT);

  attn<<<dim3(LSEQ / 64, HEADS), 256, 0, stream>>>(Qb, Kb, Vb, Ob);

  gemm_bt<true><<<ggrid, 256, 0, stream>>>(Ob, Wob, bo, d_out, LSEQ, DIM, DIM);
}